// Round 2
// baseline (504.338 us; speedup 1.0000x reference)
//
#include <hip/hip_runtime.h>

// GRUModel: 2-layer GRU (H=64), B=4096, T=512, fp32 in/out — MFMA round 13.
//
// R13 = R12 (375us dispatch, VALUBusy 54%) with v_exp_f32 ELIMINATED.
// Calibration from measured VALUBusy (947 cyc/SIMD/window, ~65 full-rate +
// 12 trans per wave): v_exp_f32 costs ~28-32 cyc/wave64 — trans still eats
// ~650 of 947 VALU cycles. Replace with full-rate poly:
//   exp2_fast(x): f = x - rint(x) in [-0.5,0.5]; deg-5 Taylor (abs err 8e-7,
//   << fp16 h quantum 4.9e-4); 2^i via v_ldexp_f32.
//   = rndne + sub + 5 fma + cvt_i32 + ldexp = 9 full-rate (18 cyc) vs ~30.
// Sign folded into weights: pre-scales are now -log2e / -2log2e so the MFMA
// accumulators ARE the poly arguments (no negation instructions).
//
// Structure (R8): 256 blocks x 512 threads; waves 0-3 layer 0 @ window k,
// waves 4-7 layer 1 @ k-1; single fp16 MFMA operands; one barrier/window;
// parity double-buffered h planes; h-state fp32 in registers.
//
// Frag layouts (m89/m120-verified):
//   A: lane holds A[m=lane&15][k=(lane>>4)*8+j], j=0..7
//   B: lane holds B[k=(lane>>4)*8+j][n=lane&15]
//   C/D: lane holds D[m=(lane>>4)*4+reg][n=lane&15]

typedef _Float16 half8 __attribute__((ext_vector_type(8)));
typedef float    v4f   __attribute__((ext_vector_type(4)));

#define T_LEN 512
#define KS 72   // fp16 row stride of h planes (16B-aligned b128 reads)

#define L2E  1.4426950408889634f   // log2(e)
#define L2E2 2.8853900817779268f   // 2*log2(e)

static __device__ __forceinline__ v4f mfma16(half8 a, half8 b, v4f c) {
    return __builtin_amdgcn_mfma_f32_16x16x32_f16(a, b, c, 0, 0, 0);
}
static __device__ __forceinline__ half8 ld8(const _Float16* p) {
    return *(const half8*)p;
}
// full-rate reciprocal: magic seed (rel err ~3.4e-2) + 2 Newton -> ~1.3e-6
static __device__ __forceinline__ float rcp_fast(float d) {
    float y = __builtin_bit_cast(float, 0x7EF127EAu - __builtin_bit_cast(unsigned, d));
    y = y * (2.0f - d * y);
    y = y * (2.0f - d * y);
    return y;
}
// full-rate exp2: f = x - rint(x) in [-0.5, 0.5]; 2^f deg-5 Taylor
// (abs err ~8e-7); scale by 2^i via ldexp. 9 full-rate instr, no trans.
static __device__ __forceinline__ float exp2_fast(float x) {
    const float fl = __builtin_rintf(x);     // v_rndne_f32
    const float f  = x - fl;
    float p = fmaf(f, 0.0013333558f, 0.0096181291f);
    p = fmaf(f, p, 0.0555041087f);
    p = fmaf(f, p, 0.2402265070f);
    p = fmaf(f, p, 0.6931471806f);
    p = fmaf(f, p, 1.0f);
    return __builtin_amdgcn_ldexpf(p, (int)fl);  // v_ldexp_f32
}
// merged GRU cell; inputs PRE-NEGATED & log2-scaled:
//   ar2 = -log2e*(i_r+h_r), az2 = -log2e*(i_z+h_z),
//   ni2 = -2log2e*i_n,      nh2 = -2log2e*h_n.
//   r = sigm(ar), z = sigm(az), n = tanh(i_n + r*h_n), h' = n + z*(h-n)
//   == [A(1-B) + h(1+B)] / [(1+A)(1+B)]; A=2^az2, B=2^wn, wn=ni2+r*nh2
static __device__ __forceinline__ float gru_cell(float ar2, float az2,
                                                 float ni2, float nh2, float h) {
    const float C  = exp2_fast(ar2);          // e^{-ar}
    const float r  = rcp_fast(1.0f + C);
    const float wn = fmaf(r, nh2, ni2);       // = -2log2e*(i_n + r*h_n)
    const float A  = exp2_fast(az2);          // e^{-az}
    const float Bv = exp2_fast(wn);           // e^{-2(i_n + r*h_n)}
    const float aB = 1.0f + Bv;
    const float num = fmaf(h, aB, A * (1.0f - Bv));
    const float den = (1.0f + A) * aB;
    return num * rcp_fast(den);
}

__global__ __launch_bounds__(512, 1)
void gru_mfma(const float* __restrict__ x,
              const float* __restrict__ w_ih0, const float* __restrict__ w_hh0,
              const float* __restrict__ b_ih0, const float* __restrict__ b_hh0,
              const float* __restrict__ w_ih1, const float* __restrict__ w_hh1,
              const float* __restrict__ b_ih1, const float* __restrict__ b_hh1,
              const float* __restrict__ fc_w,  const float* __restrict__ fc_b,
              float* __restrict__ out)
{
    __shared__ __align__(16) float xs[T_LEN * 16];        // [t][m], 32 KB
    __shared__ __align__(16) _Float16 h0f[2][16 * KS];    // h0 fp16, 2 parities
    __shared__ __align__(16) _Float16 h1f[2][16 * KS];    // h1 fp16, 2 parities
    __shared__ float red[64];

    const int tid  = threadIdx.x;
    const int wv   = tid >> 6;
    const int grp  = wv >> 2;       // 0 = layer-0 group, 1 = layer-1 group
    const int w    = wv & 3;        // N-split within group
    const int lane = tid & 63;
    const int n    = lane & 15;
    const int q    = lane >> 4;
    const int u    = w * 16 + n;    // unit owned in gate phase

    // ---- stage this block's 16 x-rows into LDS as [t][m] (coalesced) ----
    const float* xg = x + (size_t)(blockIdx.x * 16) * T_LEN;
    for (int i = tid; i < 16 * T_LEN; i += 512) {
        const int row = i >> 9, t = i & 511;
        xs[t * 16 + row] = xg[row * T_LEN + t];
    }
    // zero parity-1 buffers (read before first write)
    for (int i = tid; i < 16 * KS; i += 512) {
        h0f[1][i] = (_Float16)0;
        h1f[1][i] = (_Float16)0;
    }

    // ---- loop-invariant weight B-fragments, pre-scaled into NEGATED log2
    // domain. grp0 uses c=0,1 (W_hh0, K=64); grp1 uses c=0..3
    // ([W_ih1 | W_hh1], K=128). gates r,z scaled by -log2e; n by -2log2e.
    half8 B[3][4];
    {
        const int rows[3] = {u, 64 + u, 128 + u};
        const float sc[3] = {-L2E, -L2E, -L2E2};
        const float* bc[4];
        if (grp == 0) {
            bc[0] = w_hh0;      bc[1] = w_hh0 + 32;
            bc[2] = w_hh0;      bc[3] = w_hh0 + 32;   // unused dups
        } else {
            bc[0] = w_ih1;      bc[1] = w_ih1 + 32;
            bc[2] = w_hh1;      bc[3] = w_hh1 + 32;
        }
        #pragma unroll
        for (int g = 0; g < 3; g++)
            #pragma unroll
            for (int c = 0; c < 4; c++) {
                const float* r0 = bc[c] + rows[g] * 64 + 8 * q;
                #pragma unroll
                for (int j = 0; j < 8; j++) B[g][c][j] = (_Float16)(r0[j] * sc[g]);
            }
    }

    // per-lane gate constants for unit u (group-specific), negated log2-scaled
    float wir = 0.f, wiz = 0.f, win = 0.f, brc = 0.f, bzc = 0.f, binc = 0.f, bhnc = 0.f;
    if (grp == 0) {
        wir = -w_ih0[u] * L2E; wiz = -w_ih0[64 + u] * L2E; win = -w_ih0[128 + u] * L2E2;
        brc = -(b_ih0[u] + b_hh0[u]) * L2E;
        bzc = -(b_ih0[64 + u] + b_hh0[64 + u]) * L2E;
        binc = -b_ih0[128 + u] * L2E2; bhnc = -b_hh0[128 + u] * L2E2;
    } else {
        brc = -(b_ih1[u] + b_hh1[u]) * L2E;
        bzc = -(b_ih1[64 + u] + b_hh1[64 + u]) * L2E;
        binc = -b_ih1[128 + u] * L2E2; bhnc = -b_hh1[128 + u] * L2E2;
    }

    // loop-invariant bias splats: fed as the C operand of the FIRST MFMA of
    // each accumulator chain (no per-step splat movs).
    const v4f biasR4  = {brc,  brc,  brc,  brc};
    const v4f biasZ4  = {bzc,  bzc,  bzc,  bzc};
    const v4f biasNi4 = {binc, binc, binc, binc};
    const v4f biasNh4 = {bhnc, bhnc, bhnc, bhnc};

    float hst[4] = {0.f, 0.f, 0.f, 0.f};   // fp32 h[m=4q+reg][u] (own layer)

    __syncthreads();

    const int abase = n * KS + 8 * q;       // A-frag base (fp16 elems)

    #pragma unroll 1
    for (int k = 0; k < T_LEN + 1; k++) {
        if (grp == 0) {
            if (k < T_LEN) {
                const int pw = k & 1, pr = pw ^ 1;
                // A-frags of h0(k-1) — written @k-1 pre-barrier, visible now
                const half8 a0 = ld8(&h0f[pr][abase]);
                const half8 a1 = ld8(&h0f[pr][abase + 32]);
                const v4f xv = *(const v4f*)(xs + k * 16 + 4 * q);  // broadcast

                v4f accR, accZ;
                #pragma unroll
                for (int r = 0; r < 4; r++) {
                    accR[r] = fmaf(xv[r], wir, brc);
                    accZ[r] = fmaf(xv[r], wiz, bzc);
                }
                v4f accN = mfma16(a0, B[2][0], biasNh4);   // bhnc folded in
                accR = mfma16(a0, B[0][0], accR);
                accZ = mfma16(a0, B[1][0], accZ);
                accN = mfma16(a1, B[2][1], accN);
                accR = mfma16(a1, B[0][1], accR);
                accZ = mfma16(a1, B[1][1], accZ);

                #pragma unroll
                for (int r = 0; r < 4; r++) {
                    const float inn = fmaf(xv[r], win, binc);
                    const float h = gru_cell(accR[r], accZ[r],
                                             inn, accN[r], hst[r]);
                    hst[r] = h;
                    h0f[pw][(4 * q + r) * KS + u] = (_Float16)h;
                }
            }
        } else {
            if (k > 0) {
                const int t = k - 1;
                const int pw = t & 1;       // h0(t) parity; h1(t) write parity
                const int p1 = pw ^ 1;      // h1(t-1) parity
                const half8 g00 = ld8(&h0f[pw][abase]);        // h0new(t)
                const half8 g01 = ld8(&h0f[pw][abase + 32]);
                const half8 g10 = ld8(&h1f[p1][abase]);        // h1(t-1)
                const half8 g11 = ld8(&h1f[p1][abase + 32]);

                // r,z fold i-side and h-side into one acc; n keeps them apart
                v4f aR  = mfma16(g00, B[0][0], biasR4);
                v4f aZ  = mfma16(g00, B[1][0], biasZ4);
                v4f aNi = mfma16(g00, B[2][0], biasNi4);
                v4f aNh = mfma16(g10, B[2][2], biasNh4);
                aR  = mfma16(g01, B[0][1], aR);
                aZ  = mfma16(g01, B[1][1], aZ);
                aNi = mfma16(g01, B[2][1], aNi);
                aNh = mfma16(g11, B[2][3], aNh);
                aR  = mfma16(g10, B[0][2], aR);
                aZ  = mfma16(g10, B[1][2], aZ);
                aR  = mfma16(g11, B[0][3], aR);
                aZ  = mfma16(g11, B[1][3], aZ);

                #pragma unroll
                for (int r = 0; r < 4; r++) {
                    const float h = gru_cell(aR[r], aZ[r],
                                             aNi[r], aNh[r], hst[r]);
                    hst[r] = h;
                    h1f[pw][(4 * q + r) * KS + u] = (_Float16)h;
                }
            }
        }
        __syncthreads();   // the ONE barrier per window (anti-dependence)
    }

    // ======== FC epilogue: out[m] = sum_u fc_w[u] h1[m][u] + fc_b ========
    if (grp == 1) {
        const float fw = fc_w[u];
        #pragma unroll
        for (int r = 0; r < 4; r++) {
            float v = fw * hst[r];
            v += __shfl_xor(v, 1, 64);
            v += __shfl_xor(v, 2, 64);
            v += __shfl_xor(v, 4, 64);
            v += __shfl_xor(v, 8, 64);   // sum over 16 n-lanes (q preserved)
            if (n == 0) red[(4 * q + r) * 4 + w] = v;
        }
    }
    __syncthreads();
    if (tid < 16) {
        const float s = red[tid * 4] + red[tid * 4 + 1] + red[tid * 4 + 2] + red[tid * 4 + 3];
        out[blockIdx.x * 16 + tid] = s + fc_b[0];
    }
}

extern "C" void kernel_launch(void* const* d_in, const int* in_sizes, int n_in,
                              void* d_out, int out_size, void* d_ws, size_t ws_size,
                              hipStream_t stream)
{
    const float* x     = (const float*)d_in[0];
    const float* w_ih0 = (const float*)d_in[1];
    const float* w_hh0 = (const float*)d_in[2];
    const float* b_ih0 = (const float*)d_in[3];
    const float* b_hh0 = (const float*)d_in[4];
    const float* w_ih1 = (const float*)d_in[5];
    const float* w_hh1 = (const float*)d_in[6];
    const float* b_ih1 = (const float*)d_in[7];
    const float* b_hh1 = (const float*)d_in[8];
    const float* fc_w  = (const float*)d_in[9];
    const float* fc_b  = (const float*)d_in[10];
    float* out = (float*)d_out;

    hipLaunchKernelGGL(gru_mfma, dim3(256), dim3(512), 0, stream,
                       x, w_ih0, w_hh0, b_ih0, b_hh0,
                       w_ih1, w_hh1, b_ih1, b_hh1, fc_w, fc_b, out);
}

// Round 3
// 373.333 us; speedup vs baseline: 1.3509x; 1.3509x over previous
//
#include <hip/hip_runtime.h>

// GRUModel: 2-layer GRU (H=64), B=4096, T=512, fp32 in/out — MFMA round 14.
//
// R14 post-mortem model (from R12<->R13 A/B): full-rate VALU ~4.7 busy-cyc,
// v_exp_f32 ~11 busy-cyc (NOT ~30 — prior calibration was latency-confounded).
// Poly-exp2 (R13, 9 full-rate each) was a net LOSS (375->500us). Therefore:
//   - exp: hardware v_exp_f32 via __builtin_amdgcn_exp2f, args pre-negated
//     and log2-scaled in the weights (free sign, no mul). [revert R13 poly]
//   - rcp: hardware v_rcp_f32 (1 trans ~11 cyc, ~1e-7 rel) replaces the
//     5-instr magic+Newton chain (~23.5 busy-cyc, 5-deep serial). [new]
// Cell = 5 trans + 9 full-rate (was 3t+18f in R12): ~97 vs ~118 busy-cyc,
// and the serial chain through r shortens by ~4 instrs (helps the ~500-cyc
// stall share at 2 waves/SIMD).
//
// Structure (R8): 256 blocks x 512 threads; waves 0-3 layer 0 @ window k,
// waves 4-7 layer 1 @ k-1; single fp16 MFMA operands; one barrier/window;
// parity double-buffered h planes; h-state fp32 in registers.
//
// Frag layouts (m89/m120-verified):
//   A: lane holds A[m=lane&15][k=(lane>>4)*8+j], j=0..7
//   B: lane holds B[k=(lane>>4)*8+j][n=lane&15]
//   C/D: lane holds D[m=(lane>>4)*4+reg][n=lane&15]

typedef _Float16 half8 __attribute__((ext_vector_type(8)));
typedef float    v4f   __attribute__((ext_vector_type(4)));

#define T_LEN 512
#define KS 72   // fp16 row stride of h planes (16B-aligned b128 reads)

#define L2E  1.4426950408889634f   // log2(e)
#define L2E2 2.8853900817779268f   // 2*log2(e)

static __device__ __forceinline__ v4f mfma16(half8 a, half8 b, v4f c) {
    return __builtin_amdgcn_mfma_f32_16x16x32_f16(a, b, c, 0, 0, 0);
}
static __device__ __forceinline__ half8 ld8(const _Float16* p) {
    return *(const half8*)p;
}
// merged GRU cell; inputs PRE-NEGATED & log2-scaled:
//   ar2 = -log2e*(i_r+h_r), az2 = -log2e*(i_z+h_z),
//   ni2 = -2log2e*i_n,      nh2 = -2log2e*h_n.
//   r = sigm(ar), z = sigm(az), n = tanh(i_n + r*h_n), h' = n + z*(h-n)
//   == [A(1-B) + h(1+B)] / [(1+A)(1+B)]; A=2^az2, B=2^wn, wn=ni2+r*nh2
// 5 trans (3 v_exp + 2 v_rcp) + 9 full-rate.
static __device__ __forceinline__ float gru_cell(float ar2, float az2,
                                                 float ni2, float nh2, float h) {
    const float C  = __builtin_amdgcn_exp2f(ar2);       // e^{-ar}
    const float r  = __builtin_amdgcn_rcpf(1.0f + C);   // sigm(ar)
    const float wn = fmaf(r, nh2, ni2);                 // = -2log2e*(i_n+r*h_n)
    const float A  = __builtin_amdgcn_exp2f(az2);       // e^{-az}
    const float Bv = __builtin_amdgcn_exp2f(wn);        // e^{-2(i_n+r*h_n)}
    const float aB = 1.0f + Bv;
    const float num = fmaf(h, aB, A * (1.0f - Bv));
    const float den = (1.0f + A) * aB;
    return num * __builtin_amdgcn_rcpf(den);
}

__global__ __launch_bounds__(512, 1)
void gru_mfma(const float* __restrict__ x,
              const float* __restrict__ w_ih0, const float* __restrict__ w_hh0,
              const float* __restrict__ b_ih0, const float* __restrict__ b_hh0,
              const float* __restrict__ w_ih1, const float* __restrict__ w_hh1,
              const float* __restrict__ b_ih1, const float* __restrict__ b_hh1,
              const float* __restrict__ fc_w,  const float* __restrict__ fc_b,
              float* __restrict__ out)
{
    __shared__ __align__(16) float xs[T_LEN * 16];        // [t][m], 32 KB
    __shared__ __align__(16) _Float16 h0f[2][16 * KS];    // h0 fp16, 2 parities
    __shared__ __align__(16) _Float16 h1f[2][16 * KS];    // h1 fp16, 2 parities
    __shared__ float red[64];

    const int tid  = threadIdx.x;
    const int wv   = tid >> 6;
    const int grp  = wv >> 2;       // 0 = layer-0 group, 1 = layer-1 group
    const int w    = wv & 3;        // N-split within group
    const int lane = tid & 63;
    const int n    = lane & 15;
    const int q    = lane >> 4;
    const int u    = w * 16 + n;    // unit owned in gate phase

    // ---- stage this block's 16 x-rows into LDS as [t][m] (coalesced) ----
    const float* xg = x + (size_t)(blockIdx.x * 16) * T_LEN;
    for (int i = tid; i < 16 * T_LEN; i += 512) {
        const int row = i >> 9, t = i & 511;
        xs[t * 16 + row] = xg[row * T_LEN + t];
    }
    // zero parity-1 buffers (read before first write)
    for (int i = tid; i < 16 * KS; i += 512) {
        h0f[1][i] = (_Float16)0;
        h1f[1][i] = (_Float16)0;
    }

    // ---- loop-invariant weight B-fragments, pre-scaled into NEGATED log2
    // domain. grp0 uses c=0,1 (W_hh0, K=64); grp1 uses c=0..3
    // ([W_ih1 | W_hh1], K=128). gates r,z scaled by -log2e; n by -2log2e.
    half8 B[3][4];
    {
        const int rows[3] = {u, 64 + u, 128 + u};
        const float sc[3] = {-L2E, -L2E, -L2E2};
        const float* bc[4];
        if (grp == 0) {
            bc[0] = w_hh0;      bc[1] = w_hh0 + 32;
            bc[2] = w_hh0;      bc[3] = w_hh0 + 32;   // unused dups
        } else {
            bc[0] = w_ih1;      bc[1] = w_ih1 + 32;
            bc[2] = w_hh1;      bc[3] = w_hh1 + 32;
        }
        #pragma unroll
        for (int g = 0; g < 3; g++)
            #pragma unroll
            for (int c = 0; c < 4; c++) {
                const float* r0 = bc[c] + rows[g] * 64 + 8 * q;
                #pragma unroll
                for (int j = 0; j < 8; j++) B[g][c][j] = (_Float16)(r0[j] * sc[g]);
            }
    }

    // per-lane gate constants for unit u (group-specific), negated log2-scaled
    float wir = 0.f, wiz = 0.f, win = 0.f, brc = 0.f, bzc = 0.f, binc = 0.f, bhnc = 0.f;
    if (grp == 0) {
        wir = -w_ih0[u] * L2E; wiz = -w_ih0[64 + u] * L2E; win = -w_ih0[128 + u] * L2E2;
        brc = -(b_ih0[u] + b_hh0[u]) * L2E;
        bzc = -(b_ih0[64 + u] + b_hh0[64 + u]) * L2E;
        binc = -b_ih0[128 + u] * L2E2; bhnc = -b_hh0[128 + u] * L2E2;
    } else {
        brc = -(b_ih1[u] + b_hh1[u]) * L2E;
        bzc = -(b_ih1[64 + u] + b_hh1[64 + u]) * L2E;
        binc = -b_ih1[128 + u] * L2E2; bhnc = -b_hh1[128 + u] * L2E2;
    }

    // loop-invariant bias splats: fed as the C operand of the FIRST MFMA of
    // each accumulator chain (no per-step splat movs).
    const v4f biasR4  = {brc,  brc,  brc,  brc};
    const v4f biasZ4  = {bzc,  bzc,  bzc,  bzc};
    const v4f biasNi4 = {binc, binc, binc, binc};
    const v4f biasNh4 = {bhnc, bhnc, bhnc, bhnc};

    float hst[4] = {0.f, 0.f, 0.f, 0.f};   // fp32 h[m=4q+reg][u] (own layer)

    __syncthreads();

    const int abase = n * KS + 8 * q;       // A-frag base (fp16 elems)

    #pragma unroll 1
    for (int k = 0; k < T_LEN + 1; k++) {
        if (grp == 0) {
            if (k < T_LEN) {
                const int pw = k & 1, pr = pw ^ 1;
                // A-frags of h0(k-1) — written @k-1 pre-barrier, visible now
                const half8 a0 = ld8(&h0f[pr][abase]);
                const half8 a1 = ld8(&h0f[pr][abase + 32]);
                const v4f xv = *(const v4f*)(xs + k * 16 + 4 * q);  // broadcast

                v4f accR, accZ;
                #pragma unroll
                for (int r = 0; r < 4; r++) {
                    accR[r] = fmaf(xv[r], wir, brc);
                    accZ[r] = fmaf(xv[r], wiz, bzc);
                }
                v4f accN = mfma16(a0, B[2][0], biasNh4);   // bhnc folded in
                accR = mfma16(a0, B[0][0], accR);
                accZ = mfma16(a0, B[1][0], accZ);
                accN = mfma16(a1, B[2][1], accN);
                accR = mfma16(a1, B[0][1], accR);
                accZ = mfma16(a1, B[1][1], accZ);

                #pragma unroll
                for (int r = 0; r < 4; r++) {
                    const float inn = fmaf(xv[r], win, binc);
                    const float h = gru_cell(accR[r], accZ[r],
                                             inn, accN[r], hst[r]);
                    hst[r] = h;
                    h0f[pw][(4 * q + r) * KS + u] = (_Float16)h;
                }
            }
        } else {
            if (k > 0) {
                const int t = k - 1;
                const int pw = t & 1;       // h0(t) parity; h1(t) write parity
                const int p1 = pw ^ 1;      // h1(t-1) parity
                const half8 g00 = ld8(&h0f[pw][abase]);        // h0new(t)
                const half8 g01 = ld8(&h0f[pw][abase + 32]);
                const half8 g10 = ld8(&h1f[p1][abase]);        // h1(t-1)
                const half8 g11 = ld8(&h1f[p1][abase + 32]);

                // r,z fold i-side and h-side into one acc; n keeps them apart
                v4f aR  = mfma16(g00, B[0][0], biasR4);
                v4f aZ  = mfma16(g00, B[1][0], biasZ4);
                v4f aNi = mfma16(g00, B[2][0], biasNi4);
                v4f aNh = mfma16(g10, B[2][2], biasNh4);
                aR  = mfma16(g01, B[0][1], aR);
                aZ  = mfma16(g01, B[1][1], aZ);
                aNi = mfma16(g01, B[2][1], aNi);
                aNh = mfma16(g11, B[2][3], aNh);
                aR  = mfma16(g10, B[0][2], aR);
                aZ  = mfma16(g10, B[1][2], aZ);
                aR  = mfma16(g11, B[0][3], aR);
                aZ  = mfma16(g11, B[1][3], aZ);

                #pragma unroll
                for (int r = 0; r < 4; r++) {
                    const float h = gru_cell(aR[r], aZ[r],
                                             aNi[r], aNh[r], hst[r]);
                    hst[r] = h;
                    h1f[pw][(4 * q + r) * KS + u] = (_Float16)h;
                }
            }
        }
        __syncthreads();   // the ONE barrier per window (anti-dependence)
    }

    // ======== FC epilogue: out[m] = sum_u fc_w[u] h1[m][u] + fc_b ========
    if (grp == 1) {
        const float fw = fc_w[u];
        #pragma unroll
        for (int r = 0; r < 4; r++) {
            float v = fw * hst[r];
            v += __shfl_xor(v, 1, 64);
            v += __shfl_xor(v, 2, 64);
            v += __shfl_xor(v, 4, 64);
            v += __shfl_xor(v, 8, 64);   // sum over 16 n-lanes (q preserved)
            if (n == 0) red[(4 * q + r) * 4 + w] = v;
        }
    }
    __syncthreads();
    if (tid < 16) {
        const float s = red[tid * 4] + red[tid * 4 + 1] + red[tid * 4 + 2] + red[tid * 4 + 3];
        out[blockIdx.x * 16 + tid] = s + fc_b[0];
    }
}

extern "C" void kernel_launch(void* const* d_in, const int* in_sizes, int n_in,
                              void* d_out, int out_size, void* d_ws, size_t ws_size,
                              hipStream_t stream)
{
    const float* x     = (const float*)d_in[0];
    const float* w_ih0 = (const float*)d_in[1];
    const float* w_hh0 = (const float*)d_in[2];
    const float* b_ih0 = (const float*)d_in[3];
    const float* b_hh0 = (const float*)d_in[4];
    const float* w_ih1 = (const float*)d_in[5];
    const float* w_hh1 = (const float*)d_in[6];
    const float* b_ih1 = (const float*)d_in[7];
    const float* b_hh1 = (const float*)d_in[8];
    const float* fc_w  = (const float*)d_in[9];
    const float* fc_b  = (const float*)d_in[10];
    float* out = (float*)d_out;

    hipLaunchKernelGGL(gru_mfma, dim3(256), dim3(512), 0, stream,
                       x, w_ih0, w_hh0, b_ih0, b_hh0,
                       w_ih1, w_hh1, b_ih1, b_hh1, fc_w, fc_b, out);
}

// Round 4
// 351.807 us; speedup vs baseline: 1.4336x; 1.0612x over previous
//
#include <hip/hip_runtime.h>

// GRUModel: 2-layer GRU (H=64), B=4096, T=512, fp32 in/out — MFMA round 15.
//
// Calibrated model (R12/R13/R14 A/B): full-rate VALU ~4.5 busy-cyc, trans ~10.
// Window 1581 cyc = 827 VALU + 313 MFMA + ~440 stall. Cell math (8 cells x
// (9 full + 5 trans) ~ 724 cyc) IS the VALU budget. R15 attacks the rest:
//   - x-side of layer 0 folded into MFMA: x staged as fp16 packed (0<<16)|x
//     in LDS, so one ds_read_b32 IS A-frag word0 (elem1=0); third K=32 chunk
//     (x at k-slot 0, w_ih0 rows in B) replaces 12 fma/grp0-step with 3 MFMA
//     on the 20%-busy matrix pipe. grp0: 6->9 MFMA, -12 fma.
//   - gru_cell2: 2 cells per call on float2 (ext_vector) with elementwise
//     fma/ops — lets clang form v_pk_{fma,add,mul}_f32 (VOP3P packed f32,
//     halves full-rate instr count); identical codegen to scalar if not.
//
// Structure (R8): 256 blocks x 512 threads; waves 0-3 layer 0 @ window k,
// waves 4-7 layer 1 @ k-1; single fp16 MFMA operands; one barrier/window;
// parity double-buffered h planes; h-state fp32 in registers.
//
// Frag layouts (m89/m120-verified):
//   A: lane holds A[m=lane&15][k=(lane>>4)*8+j], j=0..7
//   B: lane holds B[k=(lane>>4)*8+j][n=lane&15]
//   C/D: lane holds D[m=(lane>>4)*4+reg][n=lane&15]

typedef _Float16 half8 __attribute__((ext_vector_type(8)));
typedef float    v4f   __attribute__((ext_vector_type(4)));
typedef float    v2f   __attribute__((ext_vector_type(2)));
typedef unsigned uint4v __attribute__((ext_vector_type(4)));

#define T_LEN 512
#define KS 72   // fp16 row stride of h planes (16B-aligned b128 reads)

#define L2E  1.4426950408889634f   // log2(e)
#define L2E2 2.8853900817779268f   // 2*log2(e)

static __device__ __forceinline__ v4f mfma16(half8 a, half8 b, v4f c) {
    return __builtin_amdgcn_mfma_f32_16x16x32_f16(a, b, c, 0, 0, 0);
}
static __device__ __forceinline__ half8 ld8(const _Float16* p) {
    return *(const half8*)p;
}
static __device__ __forceinline__ v2f exp2v(v2f x) {
    v2f r; r.x = __builtin_amdgcn_exp2f(x.x); r.y = __builtin_amdgcn_exp2f(x.y);
    return r;
}
static __device__ __forceinline__ v2f rcpv(v2f x) {
    v2f r; r.x = __builtin_amdgcn_rcpf(x.x); r.y = __builtin_amdgcn_rcpf(x.y);
    return r;
}
// merged GRU cell x2; inputs PRE-NEGATED & log2-scaled:
//   ar2 = -log2e*(i_r+h_r), az2 = -log2e*(i_z+h_z),
//   ni2 = -2log2e*i_n,      nh2 = -2log2e*h_n.
//   h' = [A(1-B) + h(1+B)] / [(1+A)(1+B)]; A=2^az2, B=2^wn, wn=ni2+r*nh2
// per pair: 10 trans (6 v_exp + 4 v_rcp) + 9 packed full-rate.
static __device__ __forceinline__ v2f gru_cell2(v2f ar2, v2f az2,
                                                v2f ni2, v2f nh2, v2f h) {
    const v2f C  = exp2v(ar2);                          // e^{-ar}
    const v2f r  = rcpv(C + 1.0f);                      // sigm(ar)
    const v2f wn = __builtin_elementwise_fma(r, nh2, ni2);
    const v2f A  = exp2v(az2);                          // e^{-az}
    const v2f Bv = exp2v(wn);                           // e^{-2(i_n+r*h_n)}
    const v2f aB = Bv + 1.0f;
    const v2f num = __builtin_elementwise_fma(h, aB, A * (1.0f - Bv));
    const v2f den = (A + 1.0f) * aB;
    return num * rcpv(den);
}

__global__ __launch_bounds__(512, 1)
void gru_mfma(const float* __restrict__ x,
              const float* __restrict__ w_ih0, const float* __restrict__ w_hh0,
              const float* __restrict__ b_ih0, const float* __restrict__ b_hh0,
              const float* __restrict__ w_ih1, const float* __restrict__ w_hh1,
              const float* __restrict__ b_ih1, const float* __restrict__ b_hh1,
              const float* __restrict__ fc_w,  const float* __restrict__ fc_b,
              float* __restrict__ out)
{
    // xh32[t][m]: fp16(x) in low 16 bits, high 16 = 0 — so a single
    // ds_read_b32 IS word0 of the x A-frag (elem0 = x, elem1 = 0).
    __shared__ __align__(16) unsigned xh32[T_LEN * 16];   // 32 KB
    __shared__ __align__(16) _Float16 h0f[2][16 * KS];    // h0 fp16, 2 parities
    __shared__ __align__(16) _Float16 h1f[2][16 * KS];    // h1 fp16, 2 parities
    __shared__ float red[64];

    const int tid  = threadIdx.x;
    const int wv   = tid >> 6;
    const int grp  = wv >> 2;       // 0 = layer-0 group, 1 = layer-1 group
    const int w    = wv & 3;        // N-split within group
    const int lane = tid & 63;
    const int n    = lane & 15;
    const int q    = lane >> 4;
    const int u    = w * 16 + n;    // unit owned in gate phase

    // ---- stage this block's 16 x-rows into LDS as fp16-packed [t][m] ----
    const float* xg = x + (size_t)(blockIdx.x * 16) * T_LEN;
    for (int i = tid; i < 16 * T_LEN; i += 512) {
        const int row = i >> 9, t = i & 511;
        const float v = xg[row * T_LEN + t];
        xh32[t * 16 + row] =
            (unsigned)__builtin_bit_cast(unsigned short, (_Float16)v);
    }
    // zero parity-1 buffers (read before first write)
    for (int i = tid; i < 16 * KS; i += 512) {
        h0f[1][i] = (_Float16)0;
        h1f[1][i] = (_Float16)0;
    }

    // ---- loop-invariant weight B-fragments, pre-scaled into NEGATED log2
    // domain. grp0 uses c=0,1 (W_hh0, K=64); grp1 uses c=0..3
    // ([W_ih1 | W_hh1], K=128). gates r,z scaled by -log2e; n by -2log2e.
    half8 B[3][4];
    {
        const int rows[3] = {u, 64 + u, 128 + u};
        const float sc[3] = {-L2E, -L2E, -L2E2};
        const float* bc[4];
        if (grp == 0) {
            bc[0] = w_hh0;      bc[1] = w_hh0 + 32;
            bc[2] = w_hh0;      bc[3] = w_hh0 + 32;   // unused dups
        } else {
            bc[0] = w_ih1;      bc[1] = w_ih1 + 32;
            bc[2] = w_hh1;      bc[3] = w_hh1 + 32;
        }
        #pragma unroll
        for (int g = 0; g < 3; g++)
            #pragma unroll
            for (int c = 0; c < 4; c++) {
                const float* r0 = bc[c] + rows[g] * 64 + 8 * q;
                #pragma unroll
                for (int j = 0; j < 8; j++) B[g][c][j] = (_Float16)(r0[j] * sc[g]);
            }
    }

    // ---- x-chunk B-frags (grp0 only): Bx row k=0 = scaled w_ih0 gate row,
    // rows 1..31 = 0  ->  lane (q==0, j==0) holds w, all else 0.
    half8 BX[3];
    {
        const float sc3[3] = {-L2E, -L2E, -L2E2};
        #pragma unroll
        for (int g = 0; g < 3; g++) {
            uint4v z = {0u, 0u, 0u, 0u};
            if (grp == 0 && q == 0) {
                const _Float16 wv16 = (_Float16)(w_ih0[g * 64 + u] * sc3[g]);
                z.x = (unsigned)__builtin_bit_cast(unsigned short, wv16);
            }
            BX[g] = __builtin_bit_cast(half8, z);
        }
    }

    // per-lane gate bias constants for unit u (group-specific), -log2 scaled
    float brc, bzc, binc, bhnc;
    if (grp == 0) {
        brc = -(b_ih0[u] + b_hh0[u]) * L2E;
        bzc = -(b_ih0[64 + u] + b_hh0[64 + u]) * L2E;
        binc = -b_ih0[128 + u] * L2E2; bhnc = -b_hh0[128 + u] * L2E2;
    } else {
        brc = -(b_ih1[u] + b_hh1[u]) * L2E;
        bzc = -(b_ih1[64 + u] + b_hh1[64 + u]) * L2E;
        binc = -b_ih1[128 + u] * L2E2; bhnc = -b_hh1[128 + u] * L2E2;
    }

    // loop-invariant bias splats: C operand of the FIRST MFMA of each chain.
    const v4f biasR4  = {brc,  brc,  brc,  brc};
    const v4f biasZ4  = {bzc,  bzc,  bzc,  bzc};
    const v4f biasNi4 = {binc, binc, binc, binc};
    const v4f biasNh4 = {bhnc, bhnc, bhnc, bhnc};

    v2f hA = {0.f, 0.f}, hB = {0.f, 0.f};   // fp32 h[m=4q+{0,1,2,3}][u]

    __syncthreads();

    const int abase = n * KS + 8 * q;       // A-frag base (fp16 elems)

    #pragma unroll 1
    for (int k = 0; k < T_LEN + 1; k++) {
        if (grp == 0) {
            if (k < T_LEN) {
                const int pw = k & 1, pr = pw ^ 1;
                // A-frags of h0(k-1) — written @k-1 pre-barrier, visible now
                const half8 a0 = ld8(&h0f[pr][abase]);
                const half8 a1 = ld8(&h0f[pr][abase + 32]);
                // x A-frag: k-slot 0 = x[m=n][t=k] (only q==0 lanes non-zero)
                const unsigned xw = xh32[k * 16 + n];
                uint4v ax32 = {0u, 0u, 0u, 0u};
                ax32.x = (q == 0) ? xw : 0u;
                const half8 ax = __builtin_bit_cast(half8, ax32);

                v4f accR = mfma16(ax, BX[0], biasR4);
                v4f accZ = mfma16(ax, BX[1], biasZ4);
                v4f aNi  = mfma16(ax, BX[2], biasNi4);
                v4f accN = mfma16(a0, B[2][0], biasNh4);
                accR = mfma16(a0, B[0][0], accR);
                accZ = mfma16(a0, B[1][0], accZ);
                accN = mfma16(a1, B[2][1], accN);
                accR = mfma16(a1, B[0][1], accR);
                accZ = mfma16(a1, B[1][1], accZ);

                const v2f h01 = gru_cell2((v2f){accR[0], accR[1]},
                                          (v2f){accZ[0], accZ[1]},
                                          (v2f){aNi[0],  aNi[1]},
                                          (v2f){accN[0], accN[1]}, hA);
                const v2f h23 = gru_cell2((v2f){accR[2], accR[3]},
                                          (v2f){accZ[2], accZ[3]},
                                          (v2f){aNi[2],  aNi[3]},
                                          (v2f){accN[2], accN[3]}, hB);
                hA = h01; hB = h23;
                _Float16* wp = &h0f[pw][(4 * q) * KS + u];
                wp[0]      = (_Float16)h01.x;
                wp[KS]     = (_Float16)h01.y;
                wp[2 * KS] = (_Float16)h23.x;
                wp[3 * KS] = (_Float16)h23.y;
            }
        } else {
            if (k > 0) {
                const int t = k - 1;
                const int pw = t & 1;       // h0(t) parity; h1(t) write parity
                const int p1 = pw ^ 1;      // h1(t-1) parity
                const half8 g00 = ld8(&h0f[pw][abase]);        // h0new(t)
                const half8 g01 = ld8(&h0f[pw][abase + 32]);
                const half8 g10 = ld8(&h1f[p1][abase]);        // h1(t-1)
                const half8 g11 = ld8(&h1f[p1][abase + 32]);

                // r,z fold i-side and h-side into one acc; n keeps them apart
                v4f aR  = mfma16(g00, B[0][0], biasR4);
                v4f aZ  = mfma16(g00, B[1][0], biasZ4);
                v4f aNi = mfma16(g00, B[2][0], biasNi4);
                v4f aNh = mfma16(g10, B[2][2], biasNh4);
                aR  = mfma16(g01, B[0][1], aR);
                aZ  = mfma16(g01, B[1][1], aZ);
                aNi = mfma16(g01, B[2][1], aNi);
                aNh = mfma16(g11, B[2][3], aNh);
                aR  = mfma16(g10, B[0][2], aR);
                aZ  = mfma16(g10, B[1][2], aZ);
                aR  = mfma16(g11, B[0][3], aR);
                aZ  = mfma16(g11, B[1][3], aZ);

                const v2f h01 = gru_cell2((v2f){aR[0], aR[1]},
                                          (v2f){aZ[0], aZ[1]},
                                          (v2f){aNi[0], aNi[1]},
                                          (v2f){aNh[0], aNh[1]}, hA);
                const v2f h23 = gru_cell2((v2f){aR[2], aR[3]},
                                          (v2f){aZ[2], aZ[3]},
                                          (v2f){aNi[2], aNi[3]},
                                          (v2f){aNh[2], aNh[3]}, hB);
                hA = h01; hB = h23;
                _Float16* wp = &h1f[pw][(4 * q) * KS + u];
                wp[0]      = (_Float16)h01.x;
                wp[KS]     = (_Float16)h01.y;
                wp[2 * KS] = (_Float16)h23.x;
                wp[3 * KS] = (_Float16)h23.y;
            }
        }
        __syncthreads();   // the ONE barrier per window (anti-dependence)
    }

    // ======== FC epilogue: out[m] = sum_u fc_w[u] h1[m][u] + fc_b ========
    if (grp == 1) {
        const float fw = fc_w[u];
        const float hv[4] = {hA.x, hA.y, hB.x, hB.y};
        #pragma unroll
        for (int r = 0; r < 4; r++) {
            float v = fw * hv[r];
            v += __shfl_xor(v, 1, 64);
            v += __shfl_xor(v, 2, 64);
            v += __shfl_xor(v, 4, 64);
            v += __shfl_xor(v, 8, 64);   // sum over 16 n-lanes (q preserved)
            if (n == 0) red[(4 * q + r) * 4 + w] = v;
        }
    }
    __syncthreads();
    if (tid < 16) {
        const float s = red[tid * 4] + red[tid * 4 + 1] + red[tid * 4 + 2] + red[tid * 4 + 3];
        out[blockIdx.x * 16 + tid] = s + fc_b[0];
    }
}

extern "C" void kernel_launch(void* const* d_in, const int* in_sizes, int n_in,
                              void* d_out, int out_size, void* d_ws, size_t ws_size,
                              hipStream_t stream)
{
    const float* x     = (const float*)d_in[0];
    const float* w_ih0 = (const float*)d_in[1];
    const float* w_hh0 = (const float*)d_in[2];
    const float* b_ih0 = (const float*)d_in[3];
    const float* b_hh0 = (const float*)d_in[4];
    const float* w_ih1 = (const float*)d_in[5];
    const float* w_hh1 = (const float*)d_in[6];
    const float* b_ih1 = (const float*)d_in[7];
    const float* b_hh1 = (const float*)d_in[8];
    const float* fc_w  = (const float*)d_in[9];
    const float* fc_b  = (const float*)d_in[10];
    float* out = (float*)d_out;

    hipLaunchKernelGGL(gru_mfma, dim3(256), dim3(512), 0, stream,
                       x, w_ih0, w_hh0, b_ih0, b_hh0,
                       w_ih1, w_hh1, b_ih1, b_hh1, fc_w, fc_b, out);
}

// Round 5
// 322.679 us; speedup vs baseline: 1.5630x; 1.0903x over previous
//
#include <hip/hip_runtime.h>

// GRUModel: 2-layer GRU (H=64), B=4096, T=512, fp32 in/out — MFMA round 16.
//
// Model (calibrated R12-R15): window 1497 cyc = 692 VALU + 360 MFMA + 445
// stall. Trans (400 cyc) and MFMA counts are at algorithmic floor. R16
// attacks loop overhead + stall, no numerics changes:
//   - 2x-unrolled window loop (peel k=0 and k=T): parity pw/pr/p1 are
//     compile-time literals -> LDS plane addresses fold to constants,
//     removing per-window parity+pointer VALU.
//   - s_setprio(1) around MFMA clusters (T5): grp0@k / grp1@k-1 waves
//     co-resident per SIMD = real role-split, the regime where setprio
//     measured +4-7%.
//   - grp1 issues h1-side reads/MFMAs first (data written a full window
//     ago) so 6 of 12 MFMAs start before h0(t) frags arrive.
//
// Structure (R8): 256 blocks x 512 threads; waves 0-3 layer 0 @ window k,
// waves 4-7 layer 1 @ k-1; single fp16 MFMA operands; one barrier/window;
// parity double-buffered h planes; h-state fp32 in registers.
//
// Frag layouts (m89/m120-verified):
//   A: lane holds A[m=lane&15][k=(lane>>4)*8+j], j=0..7
//   B: lane holds B[k=(lane>>4)*8+j][n=lane&15]
//   C/D: lane holds D[m=(lane>>4)*4+reg][n=lane&15]

typedef _Float16 half8 __attribute__((ext_vector_type(8)));
typedef float    v4f   __attribute__((ext_vector_type(4)));
typedef float    v2f   __attribute__((ext_vector_type(2)));
typedef unsigned uint4v __attribute__((ext_vector_type(4)));

#define T_LEN 512
#define KS 72   // fp16 row stride of h planes (16B-aligned b128 reads)

#define L2E  1.4426950408889634f   // log2(e)
#define L2E2 2.8853900817779268f   // 2*log2(e)

static __device__ __forceinline__ v4f mfma16(half8 a, half8 b, v4f c) {
    return __builtin_amdgcn_mfma_f32_16x16x32_f16(a, b, c, 0, 0, 0);
}
static __device__ __forceinline__ half8 ld8(const _Float16* p) {
    return *(const half8*)p;
}
static __device__ __forceinline__ v2f exp2v(v2f x) {
    v2f r; r.x = __builtin_amdgcn_exp2f(x.x); r.y = __builtin_amdgcn_exp2f(x.y);
    return r;
}
static __device__ __forceinline__ v2f rcpv(v2f x) {
    v2f r; r.x = __builtin_amdgcn_rcpf(x.x); r.y = __builtin_amdgcn_rcpf(x.y);
    return r;
}
// merged GRU cell x2; inputs PRE-NEGATED & log2-scaled:
//   ar2 = -log2e*(i_r+h_r), az2 = -log2e*(i_z+h_z),
//   ni2 = -2log2e*i_n,      nh2 = -2log2e*h_n.
//   h' = [A(1-B) + h(1+B)] / [(1+A)(1+B)]; A=2^az2, B=2^wn, wn=ni2+r*nh2
// per pair: 10 trans (6 v_exp + 4 v_rcp) + 9 packed full-rate.
static __device__ __forceinline__ v2f gru_cell2(v2f ar2, v2f az2,
                                                v2f ni2, v2f nh2, v2f h) {
    const v2f C  = exp2v(ar2);                          // e^{-ar}
    const v2f r  = rcpv(C + 1.0f);                      // sigm(ar)
    const v2f wn = __builtin_elementwise_fma(r, nh2, ni2);
    const v2f A  = exp2v(az2);                          // e^{-az}
    const v2f Bv = exp2v(wn);                           // e^{-2(i_n+r*h_n)}
    const v2f aB = Bv + 1.0f;
    const v2f num = __builtin_elementwise_fma(h, aB, A * (1.0f - Bv));
    const v2f den = (A + 1.0f) * aB;
    return num * rcpv(den);
}

__global__ __launch_bounds__(512, 1)
void gru_mfma(const float* __restrict__ x,
              const float* __restrict__ w_ih0, const float* __restrict__ w_hh0,
              const float* __restrict__ b_ih0, const float* __restrict__ b_hh0,
              const float* __restrict__ w_ih1, const float* __restrict__ w_hh1,
              const float* __restrict__ b_ih1, const float* __restrict__ b_hh1,
              const float* __restrict__ fc_w,  const float* __restrict__ fc_b,
              float* __restrict__ out)
{
    // xh32[t][m]: fp16(x) in low 16 bits, high 16 = 0 — so a single
    // ds_read_b32 IS word0 of the x A-frag (elem0 = x, elem1 = 0).
    __shared__ __align__(16) unsigned xh32[T_LEN * 16];   // 32 KB
    __shared__ __align__(16) _Float16 h0f[2][16 * KS];    // h0 fp16, 2 parities
    __shared__ __align__(16) _Float16 h1f[2][16 * KS];    // h1 fp16, 2 parities
    __shared__ float red[64];

    const int tid  = threadIdx.x;
    const int wv   = tid >> 6;
    const int grp  = wv >> 2;       // 0 = layer-0 group, 1 = layer-1 group
    const int w    = wv & 3;        // N-split within group
    const int lane = tid & 63;
    const int n    = lane & 15;
    const int q    = lane >> 4;
    const int u    = w * 16 + n;    // unit owned in gate phase

    // ---- stage this block's 16 x-rows into LDS as fp16-packed [t][m] ----
    const float* xg = x + (size_t)(blockIdx.x * 16) * T_LEN;
    for (int i = tid; i < 16 * T_LEN; i += 512) {
        const int row = i >> 9, t = i & 511;
        const float v = xg[row * T_LEN + t];
        xh32[t * 16 + row] =
            (unsigned)__builtin_bit_cast(unsigned short, (_Float16)v);
    }
    // zero parity-1 buffers (read before first write)
    for (int i = tid; i < 16 * KS; i += 512) {
        h0f[1][i] = (_Float16)0;
        h1f[1][i] = (_Float16)0;
    }

    // ---- loop-invariant weight B-fragments, pre-scaled into NEGATED log2
    // domain. grp0 uses c=0,1 (W_hh0, K=64); grp1 uses c=0..3
    // ([W_ih1 | W_hh1], K=128). gates r,z scaled by -log2e; n by -2log2e.
    half8 B[3][4];
    {
        const int rows[3] = {u, 64 + u, 128 + u};
        const float sc[3] = {-L2E, -L2E, -L2E2};
        const float* bc[4];
        if (grp == 0) {
            bc[0] = w_hh0;      bc[1] = w_hh0 + 32;
            bc[2] = w_hh0;      bc[3] = w_hh0 + 32;   // unused dups
        } else {
            bc[0] = w_ih1;      bc[1] = w_ih1 + 32;
            bc[2] = w_hh1;      bc[3] = w_hh1 + 32;
        }
        #pragma unroll
        for (int g = 0; g < 3; g++)
            #pragma unroll
            for (int c = 0; c < 4; c++) {
                const float* r0 = bc[c] + rows[g] * 64 + 8 * q;
                #pragma unroll
                for (int j = 0; j < 8; j++) B[g][c][j] = (_Float16)(r0[j] * sc[g]);
            }
    }

    // ---- x-chunk B-frags (grp0 only): Bx row k=0 = scaled w_ih0 gate row,
    // rows 1..31 = 0  ->  lane (q==0, j==0) holds w, all else 0.
    half8 BX[3];
    {
        const float sc3[3] = {-L2E, -L2E, -L2E2};
        #pragma unroll
        for (int g = 0; g < 3; g++) {
            uint4v z = {0u, 0u, 0u, 0u};
            if (grp == 0 && q == 0) {
                const _Float16 wv16 = (_Float16)(w_ih0[g * 64 + u] * sc3[g]);
                z.x = (unsigned)__builtin_bit_cast(unsigned short, wv16);
            }
            BX[g] = __builtin_bit_cast(half8, z);
        }
    }

    // per-lane gate bias constants for unit u (group-specific), -log2 scaled
    float brc, bzc, binc, bhnc;
    if (grp == 0) {
        brc = -(b_ih0[u] + b_hh0[u]) * L2E;
        bzc = -(b_ih0[64 + u] + b_hh0[64 + u]) * L2E;
        binc = -b_ih0[128 + u] * L2E2; bhnc = -b_hh0[128 + u] * L2E2;
    } else {
        brc = -(b_ih1[u] + b_hh1[u]) * L2E;
        bzc = -(b_ih1[64 + u] + b_hh1[64 + u]) * L2E;
        binc = -b_ih1[128 + u] * L2E2; bhnc = -b_hh1[128 + u] * L2E2;
    }

    // loop-invariant bias splats: C operand of the FIRST MFMA of each chain.
    const v4f biasR4  = {brc,  brc,  brc,  brc};
    const v4f biasZ4  = {bzc,  bzc,  bzc,  bzc};
    const v4f biasNi4 = {binc, binc, binc, binc};
    const v4f biasNh4 = {bhnc, bhnc, bhnc, bhnc};

    v2f hA = {0.f, 0.f}, hB = {0.f, 0.f};   // fp32 h[m=4q+{0,1,2,3}][u]

    __syncthreads();

    const int abase = n * KS + 8 * q;       // A-frag base (fp16 elems)

    // ---- window bodies; P = window parity, a LITERAL at every call site
    // so all parity-dependent LDS addresses fold to constants.
    auto grp0_step = [&](int k, int P) __attribute__((always_inline)) {
        const int pw = P, pr = P ^ 1;
        // A-frags of h0(k-1) — written @k-1 pre-barrier, visible now
        const half8 a0 = ld8(&h0f[pr][abase]);
        const half8 a1 = ld8(&h0f[pr][abase + 32]);
        // x A-frag: k-slot 0 = x[m=n][t=k] (only q==0 lanes non-zero)
        const unsigned xw = xh32[k * 16 + n];
        uint4v ax32 = {0u, 0u, 0u, 0u};
        ax32.x = (q == 0) ? xw : 0u;
        const half8 ax = __builtin_bit_cast(half8, ax32);

        __builtin_amdgcn_s_setprio(1);
        v4f accR = mfma16(ax, BX[0], biasR4);
        v4f accZ = mfma16(ax, BX[1], biasZ4);
        v4f aNi  = mfma16(ax, BX[2], biasNi4);
        v4f accN = mfma16(a0, B[2][0], biasNh4);
        accR = mfma16(a0, B[0][0], accR);
        accZ = mfma16(a0, B[1][0], accZ);
        accN = mfma16(a1, B[2][1], accN);
        accR = mfma16(a1, B[0][1], accR);
        accZ = mfma16(a1, B[1][1], accZ);
        __builtin_amdgcn_s_setprio(0);

        const v2f h01 = gru_cell2((v2f){accR[0], accR[1]},
                                  (v2f){accZ[0], accZ[1]},
                                  (v2f){aNi[0],  aNi[1]},
                                  (v2f){accN[0], accN[1]}, hA);
        const v2f h23 = gru_cell2((v2f){accR[2], accR[3]},
                                  (v2f){accZ[2], accZ[3]},
                                  (v2f){aNi[2],  aNi[3]},
                                  (v2f){accN[2], accN[3]}, hB);
        hA = h01; hB = h23;
        _Float16* wp = &h0f[pw][(4 * q) * KS + u];
        wp[0]      = (_Float16)h01.x;
        wp[KS]     = (_Float16)h01.y;
        wp[2 * KS] = (_Float16)h23.x;
        wp[3 * KS] = (_Float16)h23.y;
    };

    auto grp1_step = [&](int P) __attribute__((always_inline)) {
        // window k has parity P; this consumes h0(t=k-1) (parity P^1) and
        // h1(t-1) (parity P), writes h1(t) at parity P^1.
        const int pw = P ^ 1, p1 = P;
        // own-layer frags first: written a full window ago, reads ready
        const half8 g10 = ld8(&h1f[p1][abase]);        // h1(t-1)
        const half8 g11 = ld8(&h1f[p1][abase + 32]);
        const half8 g00 = ld8(&h0f[pw][abase]);        // h0new(t)
        const half8 g01 = ld8(&h0f[pw][abase + 32]);

        __builtin_amdgcn_s_setprio(1);
        // h1-dependent MFMAs first (shorter post-barrier critical path)
        v4f aR  = mfma16(g10, B[0][2], biasR4);
        v4f aZ  = mfma16(g10, B[1][2], biasZ4);
        v4f aNh = mfma16(g10, B[2][2], biasNh4);
        aR  = mfma16(g11, B[0][3], aR);
        aZ  = mfma16(g11, B[1][3], aZ);
        aNh = mfma16(g11, B[2][3], aNh);
        v4f aNi = mfma16(g00, B[2][0], biasNi4);
        aR  = mfma16(g00, B[0][0], aR);
        aZ  = mfma16(g00, B[1][0], aZ);
        aNi = mfma16(g01, B[2][1], aNi);
        aR  = mfma16(g01, B[0][1], aR);
        aZ  = mfma16(g01, B[1][1], aZ);
        __builtin_amdgcn_s_setprio(0);

        const v2f h01 = gru_cell2((v2f){aR[0], aR[1]},
                                  (v2f){aZ[0], aZ[1]},
                                  (v2f){aNi[0], aNi[1]},
                                  (v2f){aNh[0], aNh[1]}, hA);
        const v2f h23 = gru_cell2((v2f){aR[2], aR[3]},
                                  (v2f){aZ[2], aZ[3]},
                                  (v2f){aNi[2], aNi[3]},
                                  (v2f){aNh[2], aNh[3]}, hB);
        hA = h01; hB = h23;
        _Float16* wp = &h1f[pw][(4 * q) * KS + u];
        wp[0]      = (_Float16)h01.x;
        wp[KS]     = (_Float16)h01.y;
        wp[2 * KS] = (_Float16)h23.x;
        wp[3 * KS] = (_Float16)h23.y;
    };

    // ---- window schedule: k=0 (grp0 only), pairs (odd,even), k=T_LEN-1,
    // then k=T_LEN (grp1 only). 513 windows total, parity literal each.
    if (grp == 0) grp0_step(0, 0);
    __syncthreads();
    #pragma unroll 1
    for (int kk = 1; kk + 1 < T_LEN; kk += 2) {
        if (grp == 0) grp0_step(kk, 1); else grp1_step(1);
        __syncthreads();
        if (grp == 0) grp0_step(kk + 1, 0); else grp1_step(0);
        __syncthreads();
    }
    if (grp == 0) grp0_step(T_LEN - 1, 1); else grp1_step(1);
    __syncthreads();
    if (grp == 1) grp1_step(0);              // window k = T_LEN, t = T_LEN-1
    __syncthreads();

    // ======== FC epilogue: out[m] = sum_u fc_w[u] h1[m][u] + fc_b ========
    if (grp == 1) {
        const float fw = fc_w[u];
        const float hv[4] = {hA.x, hA.y, hB.x, hB.y};
        #pragma unroll
        for (int r = 0; r < 4; r++) {
            float v = fw * hv[r];
            v += __shfl_xor(v, 1, 64);
            v += __shfl_xor(v, 2, 64);
            v += __shfl_xor(v, 4, 64);
            v += __shfl_xor(v, 8, 64);   // sum over 16 n-lanes (q preserved)
            if (n == 0) red[(4 * q + r) * 4 + w] = v;
        }
    }
    __syncthreads();
    if (tid < 16) {
        const float s = red[tid * 4] + red[tid * 4 + 1] + red[tid * 4 + 2] + red[tid * 4 + 3];
        out[blockIdx.x * 16 + tid] = s + fc_b[0];
    }
}

extern "C" void kernel_launch(void* const* d_in, const int* in_sizes, int n_in,
                              void* d_out, int out_size, void* d_ws, size_t ws_size,
                              hipStream_t stream)
{
    const float* x     = (const float*)d_in[0];
    const float* w_ih0 = (const float*)d_in[1];
    const float* w_hh0 = (const float*)d_in[2];
    const float* b_ih0 = (const float*)d_in[3];
    const float* b_hh0 = (const float*)d_in[4];
    const float* w_ih1 = (const float*)d_in[5];
    const float* w_hh1 = (const float*)d_in[6];
    const float* b_ih1 = (const float*)d_in[7];
    const float* b_hh1 = (const float*)d_in[8];
    const float* fc_w  = (const float*)d_in[9];
    const float* fc_b  = (const float*)d_in[10];
    float* out = (float*)d_out;

    hipLaunchKernelGGL(gru_mfma, dim3(256), dim3(512), 0, stream,
                       x, w_ih0, w_hh0, b_ih0, b_hh0,
                       w_ih1, w_hh1, b_ih1, b_hh1, fc_w, fc_b, out);
}